// Round 1
// baseline (239.460 us; speedup 1.0000x reference)
//
#include <hip/hip_runtime.h>
#include <hip/hip_bf16.h>

// Problem constants (fixed-shape problem)
#define BB   32
#define NREL 512
#define DD   1024
#define MTOT (BB * NREL)      // 16384
#define OBJ_ROWS (BB * 100)   // 3200

typedef __attribute__((ext_vector_type(8))) short bf16x8;
typedef __attribute__((ext_vector_type(4))) float f32x4;

__device__ __forceinline__ unsigned short f2bf(float f) {
    union { float f; unsigned u; } v; v.f = f;
    unsigned r = v.u + 0x7fff + ((v.u >> 16) & 1);   // RNE
    return (unsigned short)(r >> 16);
}

__device__ __forceinline__ void gld16(const void* g, void* l) {
    __builtin_amdgcn_global_load_lds(
        (const __attribute__((address_space(1))) unsigned int*)g,
        (__attribute__((address_space(3))) unsigned int*)l,
        16, 0, 0);
}

// ---- W [1024][1024] fp32 row-major -> Wt [n][k] bf16 (transpose + convert) ----
__global__ void wconv_kernel(const float* __restrict__ W, unsigned short* __restrict__ Wt) {
    __shared__ float tile[32][33];
    int k0 = blockIdx.y * 32, n0 = blockIdx.x * 32;
    int tr = threadIdx.x >> 5, tc = threadIdx.x & 31;
#pragma unroll
    for (int i = 0; i < 4; i++)
        tile[tr + i * 8][tc] = W[(size_t)(k0 + tr + i * 8) * DD + n0 + tc];
    __syncthreads();
#pragma unroll
    for (int i = 0; i < 4; i++)
        Wt[(size_t)(n0 + tr + i * 8) * DD + k0 + tc] = f2bf(tile[tc][tr + i * 8]);
}

// ---- ctx_proj[b][n] = b1[n] + sum_k ctx[b][k] * W1[1024+k][n]  (fp32 exact) ----
__global__ void ctxproj_kernel(const float* __restrict__ ctx, const float* __restrict__ W1,
                               const float* __restrict__ b1, float* __restrict__ cp) {
    int n = blockIdx.x * 256 + threadIdx.x;
    int b = blockIdx.y;
    const float* c = ctx + (size_t)b * DD;
    const float* w = W1 + (size_t)DD * DD + n;   // bottom half of W1, column n
    float acc = b1[n];
#pragma unroll 4
    for (int k = 0; k < DD; k++)
        acc = fmaf(c[k], w[(size_t)k * DD], acc);
    cp[(size_t)b * DD + n] = acc;
}

// ---- obj_vec[row][k] = bf16(0.5*(obj[g0][k] + obj[g1][k])) ----
__global__ void objvec_kernel(const float* __restrict__ obj, const int* __restrict__ pairs,
                              const int* __restrict__ num_obj, unsigned short* __restrict__ ov) {
    int row = blockIdx.x;             // 0..16383
    int b = row >> 9;
    int off = 0;
    for (int i = 0; i < b; i++) off += num_obj[i];   // block-uniform, scalar-cached
    int i0 = pairs[2 * row] + off;
    int i1 = pairs[2 * row + 1] + off;
    const float4* p0 = (const float4*)obj + (size_t)i0 * (DD / 4);
    const float4* p1 = (const float4*)obj + (size_t)i1 * (DD / 4);
    int t = threadIdx.x;              // 0..255, 4 floats each
    float4 x = p0[t], y = p1[t];
    ushort4 o;
    o.x = f2bf(0.5f * (x.x + y.x));
    o.y = f2bf(0.5f * (x.y + y.y));
    o.z = f2bf(0.5f * (x.z + y.z));
    o.w = f2bf(0.5f * (x.w + y.w));
    ((ushort4*)(ov + (size_t)row * DD))[t] = o;
}

// ---- bf16 MFMA GEMM, m97 structure: 128x128 tile, BK=32, 4 waves, 2-barrier ----
// A [M][1024] bf16 row-major; Bt [1024][1024] bf16 N-major (Bt[n][k]).
// MODE 1: bias = cp[row>>9][n], out = bf16 (h).  MODE 2: bias = b2[n], out = fp32.
template <int MODE>
__global__ void __launch_bounds__(256) gemm_kernel(
    const unsigned short* __restrict__ A,
    const unsigned short* __restrict__ Bt,
    const float* __restrict__ bias,
    void* __restrict__ Cout) {
    constexpr int K = 1024;
    __shared__ __attribute__((aligned(16))) unsigned short As[128 * 32];
    __shared__ __attribute__((aligned(16))) unsigned short Bs[128 * 32];
    int tid = threadIdx.x;
    int lane = tid & 63, wave = tid >> 6;
    int wr = wave >> 1, wc = wave & 1;
    int mBase = blockIdx.y * 128;
    int nBase = blockIdx.x * 128;

    f32x4 acc[4][4];
#pragma unroll
    for (int i = 0; i < 4; i++)
#pragma unroll
        for (int j = 0; j < 4; j++) acc[i][j] = (f32x4){0.f, 0.f, 0.f, 0.f};

    const unsigned short* Ab = A + (size_t)mBase * K;
    const unsigned short* Bb = Bt + (size_t)nBase * K;

    for (int k0 = 0; k0 < K; k0 += 32) {
        // stage both 128x32 bf16 tiles (8 KB each) via global_load_lds width-16
#pragma unroll
        for (int h = 0; h < 2; h++) {
            int c = tid + h * 256;            // chunk id 0..511
            int row = c >> 2, kc = (c & 3) * 8;
            gld16(Ab + (size_t)row * K + k0 + kc, As + c * 8);
            gld16(Bb + (size_t)row * K + k0 + kc, Bs + c * 8);
        }
        __syncthreads();                      // compiler drains vmcnt before barrier
        int lr = lane & 15, kg = (lane >> 4) * 8;
        bf16x8 af[4], bfr[4];
#pragma unroll
        for (int m = 0; m < 4; m++)
            af[m] = *(const bf16x8*)&As[(wr * 64 + m * 16 + lr) * 32 + kg];
#pragma unroll
        for (int n = 0; n < 4; n++)
            bfr[n] = *(const bf16x8*)&Bs[(wc * 64 + n * 16 + lr) * 32 + kg];
#pragma unroll
        for (int m = 0; m < 4; m++)
#pragma unroll
            for (int n = 0; n < 4; n++)
                acc[m][n] = __builtin_amdgcn_mfma_f32_16x16x32_bf16(af[m], bfr[n], acc[m][n], 0, 0, 0);
        __syncthreads();
    }

    // epilogue: bias + ReLU + store
    int lr = lane & 15, rg = (lane >> 4) * 4;
#pragma unroll
    for (int m = 0; m < 4; m++) {
#pragma unroll
        for (int n = 0; n < 4; n++) {
            int col = nBase + wc * 64 + n * 16 + lr;
            float bv = (MODE == 1) ? bias[((mBase >> 9) << 10) + col] : bias[col];
#pragma unroll
            for (int r = 0; r < 4; r++) {
                int row = mBase + wr * 64 + m * 16 + rg + r;
                float v = acc[m][n][r] + bv;
                v = v > 0.f ? v : 0.f;
                if (MODE == 1)
                    ((unsigned short*)Cout)[(size_t)row * 1024 + col] = f2bf(v);
                else
                    ((float*)Cout)[(size_t)row * 1024 + col] = v;
            }
        }
    }
}

extern "C" void kernel_launch(void* const* d_in, const int* in_sizes, int n_in,
                              void* d_out, int out_size, void* d_ws, size_t ws_size,
                              hipStream_t stream) {
    (void)in_sizes; (void)n_in; (void)out_size; (void)ws_size;
    const float* obj     = (const float*)d_in[0];
    const float* ctx     = (const float*)d_in[1];
    const int*   num_obj = (const int*)d_in[2];
    // d_in[3] = num_rels (unused by reference math)
    const int*   pairs   = (const int*)d_in[4];
    const float* W1      = (const float*)d_in[5];
    const float* b1      = (const float*)d_in[6];
    const float* W2      = (const float*)d_in[7];
    const float* b2      = (const float*)d_in[8];

    char* ws = (char*)d_ws;
    unsigned short* objvec = (unsigned short*)(ws);               // 16384*1024*2 = 33,554,432
    unsigned short* h      = (unsigned short*)(ws + 33554432);    // 33,554,432
    unsigned short* W1t    = (unsigned short*)(ws + 67108864);    // 2,097,152
    unsigned short* W2t    = (unsigned short*)(ws + 69206016);    // 2,097,152
    float*          cp     = (float*)(ws + 71303168);             // 131,072

    float* out_obj = (float*)d_out;
    float* out_f   = out_obj + (size_t)OBJ_ROWS * DD;

    // Output 0: passthrough copy
    hipMemcpyAsync(out_obj, obj, (size_t)OBJ_ROWS * DD * sizeof(float),
                   hipMemcpyDeviceToDevice, stream);

    // Weight convert+transpose (W1 top half, W2)
    wconv_kernel<<<dim3(32, 32), 256, 0, stream>>>(W1, W1t);
    wconv_kernel<<<dim3(32, 32), 256, 0, stream>>>(W2, W2t);
    // ctx @ W1_bottom + b1 (fp32 exact)
    ctxproj_kernel<<<dim3(4, 32), 256, 0, stream>>>(ctx, W1, b1, cp);
    // gather + mean -> bf16
    objvec_kernel<<<dim3(16384), 256, 0, stream>>>(obj, pairs, num_obj, objvec);
    // h = relu(objvec @ W1_top + ctx_proj)
    gemm_kernel<1><<<dim3(8, 128), 256, 0, stream>>>(objvec, W1t, cp, (void*)h);
    // out = relu(h @ W2 + b2)
    gemm_kernel<2><<<dim3(8, 128), 256, 0, stream>>>(h, W2t, b2, (void*)out_f);
}

// Round 2
// 159.361 us; speedup vs baseline: 1.5026x; 1.5026x over previous
//
#include <hip/hip_runtime.h>
#include <hip/hip_bf16.h>

// Problem constants (fixed-shape problem)
#define BB   32
#define NREL 512
#define DD   1024
#define MTOT (BB * NREL)      // 16384
#define OBJ_ROWS (BB * 100)   // 3200

typedef __attribute__((ext_vector_type(8))) short bf16x8;
typedef __attribute__((ext_vector_type(4))) float f32x4;

__device__ __forceinline__ unsigned short f2bf(float f) {
    union { float f; unsigned u; } v; v.f = f;
    unsigned r = v.u + 0x7fff + ((v.u >> 16) & 1);   // RNE
    return (unsigned short)(r >> 16);
}

__device__ __forceinline__ void gld16(const void* g, void* l) {
    __builtin_amdgcn_global_load_lds(
        (const __attribute__((address_space(1))) unsigned int*)g,
        (__attribute__((address_space(3))) unsigned int*)l,
        16, 0, 0);
}

// ---- W [1024][1024] fp32 row-major -> Wt [n][k] bf16 (transpose + convert) ----
__global__ void wconv_kernel(const float* __restrict__ W, unsigned short* __restrict__ Wt) {
    __shared__ float tile[32][33];
    int k0 = blockIdx.y * 32, n0 = blockIdx.x * 32;
    int tr = threadIdx.x >> 5, tc = threadIdx.x & 31;
#pragma unroll
    for (int i = 0; i < 4; i++)
        tile[tr + i * 8][tc] = W[(size_t)(k0 + tr + i * 8) * DD + n0 + tc];
    __syncthreads();
#pragma unroll
    for (int i = 0; i < 4; i++)
        Wt[(size_t)(n0 + tr + i * 8) * DD + k0 + tc] = f2bf(tile[tc][tr + i * 8]);
}

// ---- ctx projection, K-split 8 ways for occupancy ----
// part[s][b][n] = sum_{k in slice s} ctx[b][k] * W1[1024+k][n]   (fp32 exact)
__global__ void ctxpart_kernel(const float* __restrict__ ctx, const float* __restrict__ W1,
                               float* __restrict__ part) {
    int n = blockIdx.x * 256 + threadIdx.x;   // 0..1023
    int b = blockIdx.y;                        // 0..31
    int s = blockIdx.z;                        // 0..7
    const float* c = ctx + (size_t)b * DD + s * 128;
    const float* w = W1 + (size_t)(DD + s * 128) * DD + n;
    float a0 = 0.f, a1 = 0.f, a2 = 0.f, a3 = 0.f;
#pragma unroll 4
    for (int k = 0; k < 128; k += 4) {
        a0 = fmaf(c[k + 0], w[(size_t)(k + 0) * DD], a0);
        a1 = fmaf(c[k + 1], w[(size_t)(k + 1) * DD], a1);
        a2 = fmaf(c[k + 2], w[(size_t)(k + 2) * DD], a2);
        a3 = fmaf(c[k + 3], w[(size_t)(k + 3) * DD], a3);
    }
    part[((size_t)s * BB + b) * DD + n] = (a0 + a1) + (a2 + a3);
}

// cp[b][n] = b1[n] + sum_s part[s][b][n]
__global__ void ctxreduce_kernel(const float* __restrict__ part, const float* __restrict__ b1,
                                 float* __restrict__ cp) {
    int i = blockIdx.x * 256 + threadIdx.x;   // 0..32767
    int n = i & (DD - 1);
    float acc = b1[n];
#pragma unroll
    for (int s = 0; s < 8; s++) acc += part[(size_t)s * BB * DD + i];
    cp[i] = acc;
}

// ---- obj_vec[row][k] = bf16(0.5*(obj[g0][k] + obj[g1][k])) ----
__global__ void objvec_kernel(const float* __restrict__ obj, const int* __restrict__ pairs,
                              const int* __restrict__ num_obj, unsigned short* __restrict__ ov) {
    int row = blockIdx.x;             // 0..16383
    int b = row >> 9;
    int off = 0;
    for (int i = 0; i < b; i++) off += num_obj[i];   // block-uniform, scalar-cached
    int i0 = pairs[2 * row] + off;
    int i1 = pairs[2 * row + 1] + off;
    const float4* p0 = (const float4*)obj + (size_t)i0 * (DD / 4);
    const float4* p1 = (const float4*)obj + (size_t)i1 * (DD / 4);
    int t = threadIdx.x;              // 0..255, 4 floats each
    float4 x = p0[t], y = p1[t];
    ushort4 o;
    o.x = f2bf(0.5f * (x.x + y.x));
    o.y = f2bf(0.5f * (x.y + y.y));
    o.z = f2bf(0.5f * (x.z + y.z));
    o.w = f2bf(0.5f * (x.w + y.w));
    ((ushort4*)(ov + (size_t)row * DD))[t] = o;
}

// ---- bf16 MFMA GEMM, m97 structure: 128x128 tile, BK=32, 4 waves, 2-barrier ----
// A [M][1024] bf16 row-major; Bt [1024][1024] bf16 N-major (Bt[n][k]).
// MODE 1: bias = cp[row>>9][n], out = bf16 (h).  MODE 2: bias = b2[n], out = fp32.
template <int MODE>
__global__ void __launch_bounds__(256) gemm_kernel(
    const unsigned short* __restrict__ A,
    const unsigned short* __restrict__ Bt,
    const float* __restrict__ bias,
    void* __restrict__ Cout) {
    constexpr int K = 1024;
    __shared__ __attribute__((aligned(16))) unsigned short As[128 * 32];
    __shared__ __attribute__((aligned(16))) unsigned short Bs[128 * 32];
    int tid = threadIdx.x;
    int lane = tid & 63, wave = tid >> 6;
    int wr = wave >> 1, wc = wave & 1;
    int mBase = blockIdx.y * 128;
    int nBase = blockIdx.x * 128;

    f32x4 acc[4][4];
#pragma unroll
    for (int i = 0; i < 4; i++)
#pragma unroll
        for (int j = 0; j < 4; j++) acc[i][j] = (f32x4){0.f, 0.f, 0.f, 0.f};

    const unsigned short* Ab = A + (size_t)mBase * K;
    const unsigned short* Bb = Bt + (size_t)nBase * K;

    for (int k0 = 0; k0 < K; k0 += 32) {
        // stage both 128x32 bf16 tiles (8 KB each) via global_load_lds width-16
#pragma unroll
        for (int h = 0; h < 2; h++) {
            int c = tid + h * 256;            // chunk id 0..511
            int row = c >> 2, kc = (c & 3) * 8;
            gld16(Ab + (size_t)row * K + k0 + kc, As + c * 8);
            gld16(Bb + (size_t)row * K + k0 + kc, Bs + c * 8);
        }
        __syncthreads();                      // compiler drains vmcnt before barrier
        int lr = lane & 15, kg = (lane >> 4) * 8;
        bf16x8 af[4], bfr[4];
#pragma unroll
        for (int m = 0; m < 4; m++)
            af[m] = *(const bf16x8*)&As[(wr * 64 + m * 16 + lr) * 32 + kg];
#pragma unroll
        for (int n = 0; n < 4; n++)
            bfr[n] = *(const bf16x8*)&Bs[(wc * 64 + n * 16 + lr) * 32 + kg];
#pragma unroll
        for (int m = 0; m < 4; m++)
#pragma unroll
            for (int n = 0; n < 4; n++)
                acc[m][n] = __builtin_amdgcn_mfma_f32_16x16x32_bf16(af[m], bfr[n], acc[m][n], 0, 0, 0);
        __syncthreads();
    }

    // epilogue: bias + ReLU + store
    int lr = lane & 15, rg = (lane >> 4) * 4;
#pragma unroll
    for (int m = 0; m < 4; m++) {
#pragma unroll
        for (int n = 0; n < 4; n++) {
            int col = nBase + wc * 64 + n * 16 + lr;
            float bv = (MODE == 1) ? bias[((mBase >> 9) << 10) + col] : bias[col];
#pragma unroll
            for (int r = 0; r < 4; r++) {
                int row = mBase + wr * 64 + m * 16 + rg + r;
                float v = acc[m][n][r] + bv;
                v = v > 0.f ? v : 0.f;
                if (MODE == 1)
                    ((unsigned short*)Cout)[(size_t)row * 1024 + col] = f2bf(v);
                else
                    ((float*)Cout)[(size_t)row * 1024 + col] = v;
            }
        }
    }
}

extern "C" void kernel_launch(void* const* d_in, const int* in_sizes, int n_in,
                              void* d_out, int out_size, void* d_ws, size_t ws_size,
                              hipStream_t stream) {
    (void)in_sizes; (void)n_in; (void)out_size; (void)ws_size;
    const float* obj     = (const float*)d_in[0];
    const float* ctx     = (const float*)d_in[1];
    const int*   num_obj = (const int*)d_in[2];
    // d_in[3] = num_rels (unused by reference math)
    const int*   pairs   = (const int*)d_in[4];
    const float* W1      = (const float*)d_in[5];
    const float* b1      = (const float*)d_in[6];
    const float* W2      = (const float*)d_in[7];
    const float* b2      = (const float*)d_in[8];

    char* ws = (char*)d_ws;
    unsigned short* objvec = (unsigned short*)(ws);               // 16384*1024*2 = 33,554,432
    unsigned short* h      = (unsigned short*)(ws + 33554432);    // 33,554,432
    unsigned short* W1t    = (unsigned short*)(ws + 67108864);    // 2,097,152
    unsigned short* W2t    = (unsigned short*)(ws + 69206016);    // 2,097,152
    float*          cp     = (float*)(ws + 71303168);             // 131,072
    // ctx partials (1 MB) live in h's region: written+consumed strictly
    // before gemm_kernel<1> writes h (same-stream ordering).
    float*          part   = (float*)(ws + 33554432);

    float* out_obj = (float*)d_out;
    float* out_f   = out_obj + (size_t)OBJ_ROWS * DD;

    // Output 0: passthrough copy
    hipMemcpyAsync(out_obj, obj, (size_t)OBJ_ROWS * DD * sizeof(float),
                   hipMemcpyDeviceToDevice, stream);

    // Weight convert+transpose (W1 top half, W2)
    wconv_kernel<<<dim3(32, 32), 256, 0, stream>>>(W1, W1t);
    wconv_kernel<<<dim3(32, 32), 256, 0, stream>>>(W2, W2t);
    // ctx @ W1_bottom + b1 (fp32 exact), K-split 8 ways then reduce
    ctxpart_kernel<<<dim3(4, 32, 8), 256, 0, stream>>>(ctx, W1, part);
    ctxreduce_kernel<<<dim3(128), 256, 0, stream>>>(part, b1, cp);
    // gather + mean -> bf16
    objvec_kernel<<<dim3(16384), 256, 0, stream>>>(obj, pairs, num_obj, objvec);
    // h = relu(objvec @ W1_top + ctx_proj)
    gemm_kernel<1><<<dim3(8, 128), 256, 0, stream>>>(objvec, W1t, cp, (void*)h);
    // out = relu(h @ W2 + b2)
    gemm_kernel<2><<<dim3(8, 128), 256, 0, stream>>>(h, W2t, b2, (void*)out_f);
}

// Round 3
// 117.999 us; speedup vs baseline: 2.0293x; 1.3505x over previous
//
#include <hip/hip_runtime.h>
#include <hip/hip_bf16.h>

// Problem constants (fixed-shape problem)
#define BB   32
#define NREL 512
#define DD   1024
#define MTOT (BB * NREL)      // 16384
#define OBJ_ROWS (BB * 100)   // 3200

typedef __attribute__((ext_vector_type(8))) short bf16x8;
typedef __attribute__((ext_vector_type(4))) float f32x4;

__device__ __forceinline__ unsigned short f2bf(float f) {
    union { float f; unsigned u; } v; v.f = f;
    unsigned r = v.u + 0x7fff + ((v.u >> 16) & 1);   // RNE
    return (unsigned short)(r >> 16);
}

__device__ __forceinline__ void gld16(const void* g, void* l) {
    __builtin_amdgcn_global_load_lds(
        (const __attribute__((address_space(1))) unsigned int*)g,
        (__attribute__((address_space(3))) unsigned int*)l,
        16, 0, 0);
}

// raw barrier with compiler code-motion fences (no vmcnt drain, unlike __syncthreads)
__device__ __forceinline__ void barfence() {
    asm volatile("" ::: "memory");
    __builtin_amdgcn_s_barrier();
    asm volatile("" ::: "memory");
}

// ---- W [1024][1024] fp32 row-major -> Wt [n][k] bf16 (transpose + convert) ----
__global__ void wconv_kernel(const float* __restrict__ W, unsigned short* __restrict__ Wt) {
    __shared__ float tile[32][33];
    int k0 = blockIdx.y * 32, n0 = blockIdx.x * 32;
    int tr = threadIdx.x >> 5, tc = threadIdx.x & 31;
#pragma unroll
    for (int i = 0; i < 4; i++)
        tile[tr + i * 8][tc] = W[(size_t)(k0 + tr + i * 8) * DD + n0 + tc];
    __syncthreads();
#pragma unroll
    for (int i = 0; i < 4; i++)
        Wt[(size_t)(n0 + tr + i * 8) * DD + k0 + tc] = f2bf(tile[tc][tr + i * 8]);
}

// ---- ctx projection, K-split 8 ways for occupancy ----
__global__ void ctxpart_kernel(const float* __restrict__ ctx, const float* __restrict__ W1,
                               float* __restrict__ part) {
    int n = blockIdx.x * 256 + threadIdx.x;   // 0..1023
    int b = blockIdx.y;                        // 0..31
    int s = blockIdx.z;                        // 0..7
    const float* c = ctx + (size_t)b * DD + s * 128;
    const float* w = W1 + (size_t)(DD + s * 128) * DD + n;
    float a0 = 0.f, a1 = 0.f, a2 = 0.f, a3 = 0.f;
#pragma unroll 4
    for (int k = 0; k < 128; k += 4) {
        a0 = fmaf(c[k + 0], w[(size_t)(k + 0) * DD], a0);
        a1 = fmaf(c[k + 1], w[(size_t)(k + 1) * DD], a1);
        a2 = fmaf(c[k + 2], w[(size_t)(k + 2) * DD], a2);
        a3 = fmaf(c[k + 3], w[(size_t)(k + 3) * DD], a3);
    }
    part[((size_t)s * BB + b) * DD + n] = (a0 + a1) + (a2 + a3);
}

// cp[b][n] = b1[n] + sum_s part[s][b][n]
__global__ void ctxreduce_kernel(const float* __restrict__ part, const float* __restrict__ b1,
                                 float* __restrict__ cp) {
    int i = blockIdx.x * 256 + threadIdx.x;   // 0..32767
    int n = i & (DD - 1);
    float acc = b1[n];
#pragma unroll
    for (int s = 0; s < 8; s++) acc += part[(size_t)s * BB * DD + i];
    cp[i] = acc;
}

// ---- obj_vec[row][k] = bf16(0.5*(obj[g0][k] + obj[g1][k])) ----
__global__ void objvec_kernel(const float* __restrict__ obj, const int* __restrict__ pairs,
                              const int* __restrict__ num_obj, unsigned short* __restrict__ ov) {
    int row = blockIdx.x;             // 0..16383
    int b = row >> 9;
    int off = 0;
    for (int i = 0; i < b; i++) off += num_obj[i];   // block-uniform, scalar-cached
    int i0 = pairs[2 * row] + off;
    int i1 = pairs[2 * row + 1] + off;
    const float4* p0 = (const float4*)obj + (size_t)i0 * (DD / 4);
    const float4* p1 = (const float4*)obj + (size_t)i1 * (DD / 4);
    int t = threadIdx.x;              // 0..255, 4 floats each
    float4 x = p0[t], y = p1[t];
    ushort4 o;
    o.x = f2bf(0.5f * (x.x + y.x));
    o.y = f2bf(0.5f * (x.y + y.y));
    o.z = f2bf(0.5f * (x.z + y.z));
    o.w = f2bf(0.5f * (x.w + y.w));
    ((ushort4*)(ov + (size_t)row * DD))[t] = o;
}

// ---- bf16 MFMA GEMM: 256x256 tile, BK=64, 8 waves (2Mx4N), double-buffered LDS,
//      counted vmcnt + raw barriers (T3+T4), XOR LDS swizzle (T2, rule #21),
//      setprio around MFMA (T5), XCD-chunked block swizzle (T1).
// A [M][1024] bf16 row-major; Bt [1024][1024] bf16 N-major (Bt[n][k]).
// MODE 1: bias = cp[row>>9][n], out = bf16 (h).  MODE 2: bias = b2[n], out = fp32.
// LDS (ushort units): A0 [0,16384) A1 [16384,32768) B0 [32768,49152) B1 [49152,65536)
template <int MODE>
__global__ void __launch_bounds__(512, 2) gemm256_kernel(
    const unsigned short* __restrict__ A,
    const unsigned short* __restrict__ Bt,
    const float* __restrict__ bias,
    void* __restrict__ Cout) {
    constexpr int K = 1024;
    constexpr int NT = K / 64;   // 16 K-tiles
    extern __shared__ unsigned short lds[];
    int tid = threadIdx.x;
    int lane = tid & 63, wave = tid >> 6;
    int wr = wave >> 2, wc = wave & 3;      // 2 M-waves x 4 N-waves
    int lr = lane & 15, g = lane >> 4;

    // XCD-aware swizzle: 256 blocks, 8 XCDs -> 32 contiguous tiles per XCD (8m x 4n)
    int wg = blockIdx.x;
    int swz = (wg & 7) * 32 + (wg >> 3);
    int mBase = (swz >> 2) * 256;
    int nBase = (swz & 3) * 256;

    const unsigned short* Ab = A + (size_t)mBase * K;
    const unsigned short* Bb = Bt + (size_t)nBase * K;

    // Per-thread staging pattern (4 slots of 16B per matrix per tile).
    // LDS slot s (16B units) holds global chunk (row = s>>3, c = (s&7) ^ (row&7)).
    int srow[4], soff[4], sdst[4];
#pragma unroll
    for (int i = 0; i < 4; i++) {
        int s = i * 512 + tid;              // 0..2047
        int row = s >> 3, cperm = s & 7;
        srow[i] = row;
        soff[i] = (cperm ^ (row & 7)) * 8;  // source chunk offset (elements)
        sdst[i] = s * 8;                    // linear LDS dest (elements)
    }

    f32x4 acc[8][4];
#pragma unroll
    for (int i = 0; i < 8; i++)
#pragma unroll
        for (int j = 0; j < 4; j++) acc[i][j] = (f32x4){0.f, 0.f, 0.f, 0.f};

    auto STAGE = [&](int bi, int kt) {
        unsigned short* Ad = lds + bi * 16384;
        unsigned short* Bd = lds + 32768 + bi * 16384;
        int ko = kt * 64;
#pragma unroll
        for (int i = 0; i < 4; i++) {
            gld16(Ab + (size_t)srow[i] * K + ko + soff[i], Ad + sdst[i]);
            gld16(Bb + (size_t)srow[i] * K + ko + soff[i], Bd + sdst[i]);
        }
    };

    auto COMPUTE = [&](int bi) {
        const unsigned short* As = lds + bi * 16384;
        const unsigned short* Bs = lds + 32768 + bi * 16384;
        bf16x8 bfr[4][2];
#pragma unroll
        for (int n = 0; n < 4; n++)
#pragma unroll
            for (int kk = 0; kk < 2; kk++) {
                int row = wc * 64 + n * 16 + lr;
                int c = kk * 4 + g;
                bfr[n][kk] = *(const bf16x8*)&Bs[row * 64 + ((c ^ (row & 7)) * 8)];
            }
#pragma unroll
        for (int half = 0; half < 2; half++) {
            bf16x8 af[4][2];
#pragma unroll
            for (int m = 0; m < 4; m++)
#pragma unroll
                for (int kk = 0; kk < 2; kk++) {
                    int row = wr * 128 + (half * 4 + m) * 16 + lr;
                    int c = kk * 4 + g;
                    af[m][kk] = *(const bf16x8*)&As[row * 64 + ((c ^ (row & 7)) * 8)];
                }
            __builtin_amdgcn_s_setprio(1);
#pragma unroll
            for (int m = 0; m < 4; m++)
#pragma unroll
                for (int n = 0; n < 4; n++)
#pragma unroll
                    for (int kk = 0; kk < 2; kk++)
                        acc[half * 4 + m][n] = __builtin_amdgcn_mfma_f32_16x16x32_bf16(
                            af[m][kk], bfr[n][kk], acc[half * 4 + m][n], 0, 0, 0);
            __builtin_amdgcn_s_setprio(0);
        }
    };

    STAGE(0, 0);
    int cur = 0;
    for (int kt = 0; kt < NT - 1; ++kt) {
        STAGE(cur ^ 1, kt + 1);                         // issue next tile's 8 loads
        asm volatile("s_waitcnt vmcnt(8)" ::: "memory"); // oldest 8 (tile kt) landed
        barfence();                                      // all waves' stage(kt) visible
        COMPUTE(cur);
        barfence();                                      // all reads of buf done before overwrite
        cur ^= 1;
    }
    asm volatile("s_waitcnt vmcnt(0)" ::: "memory");
    barfence();
    COMPUTE(cur);

    // epilogue: bias + ReLU + store
    int rg = g * 4;
    int bbase = (mBase >> 9) << 10;   // batch row of cp for MODE 1
#pragma unroll
    for (int m = 0; m < 8; m++) {
#pragma unroll
        for (int n = 0; n < 4; n++) {
            int col = nBase + wc * 64 + n * 16 + lr;
            float bv = (MODE == 1) ? bias[bbase + col] : bias[col];
#pragma unroll
            for (int r = 0; r < 4; r++) {
                int row = mBase + wr * 128 + m * 16 + rg + r;
                float v = acc[m][n][r] + bv;
                v = v > 0.f ? v : 0.f;
                if (MODE == 1)
                    ((unsigned short*)Cout)[(size_t)row * 1024 + col] = f2bf(v);
                else
                    ((float*)Cout)[(size_t)row * 1024 + col] = v;
            }
        }
    }
}

extern "C" void kernel_launch(void* const* d_in, const int* in_sizes, int n_in,
                              void* d_out, int out_size, void* d_ws, size_t ws_size,
                              hipStream_t stream) {
    (void)in_sizes; (void)n_in; (void)out_size; (void)ws_size;
    const float* obj     = (const float*)d_in[0];
    const float* ctx     = (const float*)d_in[1];
    const int*   num_obj = (const int*)d_in[2];
    // d_in[3] = num_rels (unused by reference math)
    const int*   pairs   = (const int*)d_in[4];
    const float* W1      = (const float*)d_in[5];
    const float* b1      = (const float*)d_in[6];
    const float* W2      = (const float*)d_in[7];
    const float* b2      = (const float*)d_in[8];

    char* ws = (char*)d_ws;
    unsigned short* objvec = (unsigned short*)(ws);               // 33,554,432 B
    unsigned short* h      = (unsigned short*)(ws + 33554432);    // 33,554,432 B
    unsigned short* W1t    = (unsigned short*)(ws + 67108864);    // 2,097,152 B
    unsigned short* W2t    = (unsigned short*)(ws + 69206016);    // 2,097,152 B
    float*          cp     = (float*)(ws + 71303168);             // 131,072 B
    // ctx partials (1 MB) live in h's region: consumed strictly before GEMM1 writes h.
    float*          part   = (float*)(ws + 33554432);

    float* out_obj = (float*)d_out;
    float* out_f   = out_obj + (size_t)OBJ_ROWS * DD;

    // allow 128 KiB dynamic LDS (host-side, not stream-ordered; graph-capture-safe)
    hipFuncSetAttribute(reinterpret_cast<const void*>(gemm256_kernel<1>),
                        hipFuncAttributeMaxDynamicSharedMemorySize, 131072);
    hipFuncSetAttribute(reinterpret_cast<const void*>(gemm256_kernel<2>),
                        hipFuncAttributeMaxDynamicSharedMemorySize, 131072);

    // Output 0: passthrough copy
    hipMemcpyAsync(out_obj, obj, (size_t)OBJ_ROWS * DD * sizeof(float),
                   hipMemcpyDeviceToDevice, stream);

    wconv_kernel<<<dim3(32, 32), 256, 0, stream>>>(W1, W1t);
    wconv_kernel<<<dim3(32, 32), 256, 0, stream>>>(W2, W2t);
    ctxpart_kernel<<<dim3(4, 32, 8), 256, 0, stream>>>(ctx, W1, part);
    ctxreduce_kernel<<<dim3(128), 256, 0, stream>>>(part, b1, cp);
    objvec_kernel<<<dim3(16384), 256, 0, stream>>>(obj, pairs, num_obj, objvec);
    // h = relu(objvec @ W1_top + ctx_proj)
    gemm256_kernel<1><<<dim3(256), 512, 131072, stream>>>(objvec, W1t, cp, (void*)h);
    // out = relu(h @ W2 + b2)
    gemm256_kernel<2><<<dim3(256), 512, 131072, stream>>>(h, W2t, b2, (void*)out_f);
}

// Round 4
// 105.117 us; speedup vs baseline: 2.2780x; 1.1226x over previous
//
#include <hip/hip_runtime.h>
#include <hip/hip_bf16.h>

// Problem constants (fixed-shape problem)
#define BB   32
#define NREL 512
#define DD   1024
#define MTOT (BB * NREL)      // 16384
#define OBJ_ROWS (BB * 100)   // 3200

typedef __attribute__((ext_vector_type(8))) short bf16x8;
typedef __attribute__((ext_vector_type(4))) float f32x4;

__device__ __forceinline__ unsigned short f2bf(float f) {
    union { float f; unsigned u; } v; v.f = f;
    unsigned r = v.u + 0x7fff + ((v.u >> 16) & 1);   // RNE
    return (unsigned short)(r >> 16);
}

__device__ __forceinline__ void gld16(const void* g, void* l) {
    __builtin_amdgcn_global_load_lds(
        (const __attribute__((address_space(1))) unsigned int*)g,
        (__attribute__((address_space(3))) unsigned int*)l,
        16, 0, 0);
}

// raw barrier with compiler code-motion fences (no vmcnt drain, unlike __syncthreads)
__device__ __forceinline__ void barfence() {
    asm volatile("" ::: "memory");
    __builtin_amdgcn_s_barrier();
    asm volatile("" ::: "memory");
}

// ---- fused prep kernel: block-range partitioned, all branches block-uniform ----
// [0,256):      ctxproj  cp[b][n] = b1[n] + sum_k ctx[b][k]*W1[1024+k][n]  (fp32)
// [256,1280):   wconv W1 top half -> W1t (bf16, N-major)
// [1280,2304):  wconv W2          -> W2t
// [2304,6400):  objvec (4 rows/block): bf16(0.5*(obj[i0]+obj[i1]))
// [6400,8448):  passthrough copy obj -> out_obj (grid-stride float4)
__global__ void __launch_bounds__(256) prep_kernel(
    const float* __restrict__ obj, const float* __restrict__ ctx,
    const int* __restrict__ num_obj, const int* __restrict__ pairs,
    const float* __restrict__ W1, const float* __restrict__ b1,
    const float* __restrict__ W2,
    unsigned short* __restrict__ W1t, unsigned short* __restrict__ W2t,
    float* __restrict__ cp, unsigned short* __restrict__ objvec,
    float* __restrict__ out_obj) {
    __shared__ float smem[32 * 33];
    int bid = blockIdx.x;
    int tid = threadIdx.x;

    if (bid < 256) {
        // ---- ctxproj: 32 b x 8 n-chunks; 128 n x 2 k-halves per block ----
        int b = bid >> 3, chunk = bid & 7;
        int nl = tid & 127, kh = tid >> 7;
        int n = chunk * 128 + nl;
        const float* c = ctx + (size_t)b * DD + kh * 512;
        const float* w = W1 + (size_t)(DD + kh * 512) * DD + n;
        float a0 = 0.f, a1 = 0.f, a2 = 0.f, a3 = 0.f;
#pragma unroll 4
        for (int k = 0; k < 512; k += 4) {
            a0 = fmaf(c[k + 0], w[(size_t)(k + 0) * DD], a0);
            a1 = fmaf(c[k + 1], w[(size_t)(k + 1) * DD], a1);
            a2 = fmaf(c[k + 2], w[(size_t)(k + 2) * DD], a2);
            a3 = fmaf(c[k + 3], w[(size_t)(k + 3) * DD], a3);
        }
        smem[kh * 128 + nl] = (a0 + a1) + (a2 + a3);
        __syncthreads();
        if (kh == 0) cp[(size_t)b * DD + n] = smem[nl] + smem[128 + nl] + b1[n];
    } else if (bid < 2304) {
        // ---- wconv: 32x32 transpose tiles, fp32 -> bf16 N-major ----
        const float* W = (bid < 1280) ? W1 : W2;
        unsigned short* Wt = (bid < 1280) ? W1t : W2t;
        int t = (bid - 256) & 1023;
        int k0 = (t >> 5) * 32, n0 = (t & 31) * 32;
        int tr = tid >> 5, tc = tid & 31;
#pragma unroll
        for (int i = 0; i < 4; i++)
            smem[(tr + i * 8) * 33 + tc] = W[(size_t)(k0 + tr + i * 8) * DD + n0 + tc];
        __syncthreads();
#pragma unroll
        for (int i = 0; i < 4; i++)
            Wt[(size_t)(n0 + tr + i * 8) * DD + k0 + tc] = f2bf(smem[tc * 33 + tr + i * 8]);
    } else if (bid < 6400) {
        // ---- objvec: 4 rows per block (all 4 rows share a batch since 4 | 512) ----
        int rbase = (bid - 2304) * 4;
        int b = rbase >> 9;
        int off = 0;
        for (int i = 0; i < b; i++) off += num_obj[i];
#pragma unroll
        for (int rr = 0; rr < 4; rr++) {
            int row = rbase + rr;
            int i0 = pairs[2 * row] + off;
            int i1 = pairs[2 * row + 1] + off;
            float4 x = ((const float4*)obj)[(size_t)i0 * (DD / 4) + tid];
            float4 y = ((const float4*)obj)[(size_t)i1 * (DD / 4) + tid];
            ushort4 o;
            o.x = f2bf(0.5f * (x.x + y.x));
            o.y = f2bf(0.5f * (x.y + y.y));
            o.z = f2bf(0.5f * (x.z + y.z));
            o.w = f2bf(0.5f * (x.w + y.w));
            ((ushort4*)(objvec + (size_t)row * DD))[tid] = o;
        }
    } else {
        // ---- passthrough copy: 3200*1024 floats = 819200 float4 ----
        const float4* src = (const float4*)obj;
        float4* dst = (float4*)out_obj;
        for (int i = (bid - 6400) * 256 + tid; i < OBJ_ROWS * DD / 4; i += 2048 * 256)
            dst[i] = src[i];
    }
}

// ---- bf16 MFMA GEMM: 256x256 tile, BK=64, 8 waves (2Mx4N), double-buffered LDS,
//      counted vmcnt + raw barriers (T3+T4), XOR LDS swizzle (T2, rule #21),
//      setprio around MFMA (T5), XCD-chunked block swizzle (T1).
// A [M][1024] bf16 row-major; Bt [1024][1024] bf16 N-major (Bt[n][k]).
// MODE 1: bias = cp[row>>9][n], out = bf16 (h).  MODE 2: bias = b2[n], out = fp32.
// LDS (ushort units): A0 [0,16384) A1 [16384,32768) B0 [32768,49152) B1 [49152,65536)
template <int MODE>
__global__ void __launch_bounds__(512, 2) gemm256_kernel(
    const unsigned short* __restrict__ A,
    const unsigned short* __restrict__ Bt,
    const float* __restrict__ bias,
    void* __restrict__ Cout) {
    constexpr int K = 1024;
    constexpr int NT = K / 64;   // 16 K-tiles
    extern __shared__ unsigned short lds[];
    int tid = threadIdx.x;
    int lane = tid & 63, wave = tid >> 6;
    int wr = wave >> 2, wc = wave & 3;      // 2 M-waves x 4 N-waves
    int lr = lane & 15, g = lane >> 4;

    // XCD-aware swizzle: 256 blocks, 8 XCDs -> 32 contiguous tiles per XCD (8m x 4n)
    int wg = blockIdx.x;
    int swz = (wg & 7) * 32 + (wg >> 3);
    int mBase = (swz >> 2) * 256;
    int nBase = (swz & 3) * 256;

    const unsigned short* Ab = A + (size_t)mBase * K;
    const unsigned short* Bb = Bt + (size_t)nBase * K;

    // Per-thread staging pattern (4 slots of 16B per matrix per tile).
    // LDS slot s (16B units) holds global chunk (row = s>>3, c = (s&7) ^ (row&7)).
    int srow[4], soff[4], sdst[4];
#pragma unroll
    for (int i = 0; i < 4; i++) {
        int s = i * 512 + tid;              // 0..2047
        int row = s >> 3, cperm = s & 7;
        srow[i] = row;
        soff[i] = (cperm ^ (row & 7)) * 8;  // source chunk offset (elements)
        sdst[i] = s * 8;                    // linear LDS dest (elements)
    }

    f32x4 acc[8][4];
#pragma unroll
    for (int i = 0; i < 8; i++)
#pragma unroll
        for (int j = 0; j < 4; j++) acc[i][j] = (f32x4){0.f, 0.f, 0.f, 0.f};

    auto STAGE = [&](int bi, int kt) {
        unsigned short* Ad = lds + bi * 16384;
        unsigned short* Bd = lds + 32768 + bi * 16384;
        int ko = kt * 64;
#pragma unroll
        for (int i = 0; i < 4; i++) {
            gld16(Ab + (size_t)srow[i] * K + ko + soff[i], Ad + sdst[i]);
            gld16(Bb + (size_t)srow[i] * K + ko + soff[i], Bd + sdst[i]);
        }
    };

    auto COMPUTE = [&](int bi) {
        const unsigned short* As = lds + bi * 16384;
        const unsigned short* Bs = lds + 32768 + bi * 16384;
        bf16x8 bfr[4][2];
#pragma unroll
        for (int n = 0; n < 4; n++)
#pragma unroll
            for (int kk = 0; kk < 2; kk++) {
                int row = wc * 64 + n * 16 + lr;
                int c = kk * 4 + g;
                bfr[n][kk] = *(const bf16x8*)&Bs[row * 64 + ((c ^ (row & 7)) * 8)];
            }
#pragma unroll
        for (int half = 0; half < 2; half++) {
            bf16x8 af[4][2];
#pragma unroll
            for (int m = 0; m < 4; m++)
#pragma unroll
                for (int kk = 0; kk < 2; kk++) {
                    int row = wr * 128 + (half * 4 + m) * 16 + lr;
                    int c = kk * 4 + g;
                    af[m][kk] = *(const bf16x8*)&As[row * 64 + ((c ^ (row & 7)) * 8)];
                }
            __builtin_amdgcn_s_setprio(1);
#pragma unroll
            for (int m = 0; m < 4; m++)
#pragma unroll
                for (int n = 0; n < 4; n++)
#pragma unroll
                    for (int kk = 0; kk < 2; kk++)
                        acc[half * 4 + m][n] = __builtin_amdgcn_mfma_f32_16x16x32_bf16(
                            af[m][kk], bfr[n][kk], acc[half * 4 + m][n], 0, 0, 0);
            __builtin_amdgcn_s_setprio(0);
        }
    };

    STAGE(0, 0);
    int cur = 0;
    for (int kt = 0; kt < NT - 1; ++kt) {
        STAGE(cur ^ 1, kt + 1);                         // issue next tile's 8 loads
        asm volatile("s_waitcnt vmcnt(8)" ::: "memory"); // oldest 8 (tile kt) landed
        barfence();                                      // all waves' stage(kt) visible
        COMPUTE(cur);
        barfence();                                      // all reads of buf done before overwrite
        cur ^= 1;
    }
    asm volatile("s_waitcnt vmcnt(0)" ::: "memory");
    barfence();
    COMPUTE(cur);

    // epilogue: bias + ReLU + store
    int rg = g * 4;
    int bbase = (mBase >> 9) << 10;   // batch row of cp for MODE 1
#pragma unroll
    for (int m = 0; m < 8; m++) {
#pragma unroll
        for (int n = 0; n < 4; n++) {
            int col = nBase + wc * 64 + n * 16 + lr;
            float bv = (MODE == 1) ? bias[bbase + col] : bias[col];
#pragma unroll
            for (int r = 0; r < 4; r++) {
                int row = mBase + wr * 128 + m * 16 + rg + r;
                float v = acc[m][n][r] + bv;
                v = v > 0.f ? v : 0.f;
                if (MODE == 1)
                    ((unsigned short*)Cout)[(size_t)row * 1024 + col] = f2bf(v);
                else
                    ((float*)Cout)[(size_t)row * 1024 + col] = v;
            }
        }
    }
}

extern "C" void kernel_launch(void* const* d_in, const int* in_sizes, int n_in,
                              void* d_out, int out_size, void* d_ws, size_t ws_size,
                              hipStream_t stream) {
    (void)in_sizes; (void)n_in; (void)out_size; (void)ws_size;
    const float* obj     = (const float*)d_in[0];
    const float* ctx     = (const float*)d_in[1];
    const int*   num_obj = (const int*)d_in[2];
    // d_in[3] = num_rels (unused by reference math)
    const int*   pairs   = (const int*)d_in[4];
    const float* W1      = (const float*)d_in[5];
    const float* b1      = (const float*)d_in[6];
    const float* W2      = (const float*)d_in[7];
    const float* b2      = (const float*)d_in[8];

    char* ws = (char*)d_ws;
    unsigned short* objvec = (unsigned short*)(ws);               // 33,554,432 B
    unsigned short* h      = (unsigned short*)(ws + 33554432);    // 33,554,432 B
    unsigned short* W1t    = (unsigned short*)(ws + 67108864);    // 2,097,152 B
    unsigned short* W2t    = (unsigned short*)(ws + 69206016);    // 2,097,152 B
    float*          cp     = (float*)(ws + 71303168);             // 131,072 B

    float* out_obj = (float*)d_out;
    float* out_f   = out_obj + (size_t)OBJ_ROWS * DD;

    // allow 128 KiB dynamic LDS (host-side, not stream-ordered; graph-capture-safe)
    hipFuncSetAttribute(reinterpret_cast<const void*>(gemm256_kernel<1>),
                        hipFuncAttributeMaxDynamicSharedMemorySize, 131072);
    hipFuncSetAttribute(reinterpret_cast<const void*>(gemm256_kernel<2>),
                        hipFuncAttributeMaxDynamicSharedMemorySize, 131072);

    // ONE fused prep dispatch: copy + wconv x2 + ctxproj + objvec
    prep_kernel<<<dim3(8448), 256, 0, stream>>>(
        obj, ctx, num_obj, pairs, W1, b1, W2, W1t, W2t, cp, objvec, out_obj);
    // h = relu(objvec @ W1_top + ctx_proj)
    gemm256_kernel<1><<<dim3(256), 512, 131072, stream>>>(objvec, W1t, cp, (void*)h);
    // out = relu(h @ W2 + b2)
    gemm256_kernel<2><<<dim3(256), 512, 131072, stream>>>(h, W2t, b2, (void*)out_f);
}